// Round 1
// baseline (1237.143 us; speedup 1.0000x reference)
//
#include <hip/hip_runtime.h>
#include <hip/hip_bf16.h>
#include <math.h>

#define NE 6

// ---------------- RoPE tables ----------------
__global__ void rope_tables(float* __restrict__ ct, float* __restrict__ st) {
    int id = blockIdx.x * 256 + threadIdx.x;   // 2048*16
    if (id >= 2048 * 16) return;
    int s = id >> 4, f = id & 15;
    float invf = expf(-logf(10000.0f) * (float)f / 16.0f);
    float ang = (float)s * invf;
    ct[id] = cosf(ang);
    st[id] = sinf(ang);
}

// ---------------- RMSNorm ----------------
__global__ void rmsnorm_k(const float* __restrict__ x, const float* __restrict__ w,
                          float* __restrict__ o) {
    __shared__ float red[256];
    int n = blockIdx.x, t = threadIdx.x;
    float v = x[n * 256 + t];
    red[t] = v * v;
    __syncthreads();
    for (int s = 128; s > 0; s >>= 1) {
        if (t < s) red[t] += red[t + s];
        __syncthreads();
    }
    float rms = rsqrtf(red[0] / 256.0f + 1e-6f);
    o[n * 256 + t] = v * rms * w[t];
}

// ---------------- QKV GEMM: (8192x256)@(256x768), scatter to Q/K/V (B,H,S,D) ----------------
__global__ __launch_bounds__(256) void gemm_qkv(const float* __restrict__ A,
                                                const float* __restrict__ W,
                                                float* __restrict__ Q, float* __restrict__ Kq,
                                                float* __restrict__ V) {
    __shared__ float As[16][64];
    __shared__ float Bs[16][64];
    int t = threadIdx.x;
    int m0 = blockIdx.y * 64, n0 = blockIdx.x * 64;
    float acc[4][4] = {};
    int am = t >> 2, ak = (t & 3) * 4;
    int bk = t >> 4, bn = (t & 15) * 4;
    int tm = (t & 15) * 4, tn = (t >> 4) * 4;
    for (int k0 = 0; k0 < 256; k0 += 16) {
        float4 av = *(const float4*)&A[(m0 + am) * 256 + k0 + ak];
        As[ak + 0][am] = av.x; As[ak + 1][am] = av.y; As[ak + 2][am] = av.z; As[ak + 3][am] = av.w;
        float4 bv = *(const float4*)&W[(k0 + bk) * 768 + n0 + bn];
        *(float4*)&Bs[bk][bn] = bv;
        __syncthreads();
#pragma unroll
        for (int kk = 0; kk < 16; kk++) {
            float4 a4 = *(float4*)&As[kk][tm];
            float4 b4 = *(float4*)&Bs[kk][tn];
            float a[4] = {a4.x, a4.y, a4.z, a4.w};
            float b[4] = {b4.x, b4.y, b4.z, b4.w};
#pragma unroll
            for (int i = 0; i < 4; i++)
#pragma unroll
                for (int j = 0; j < 4; j++) acc[i][j] += a[i] * b[j];
        }
        __syncthreads();
    }
    int part = n0 >> 8;
    float* dst = part == 0 ? Q : (part == 1 ? Kq : V);
#pragma unroll
    for (int i = 0; i < 4; i++) {
        int rowi = m0 + tm + i;
        int b = rowi >> 11, s = rowi & 2047;
#pragma unroll
        for (int j = 0; j < 4; j++) {
            int c = n0 + tn + j;
            int e = c & 255, h = e >> 5, d = e & 31;
            dst[(((size_t)(b * 8 + h)) * 2048 + s) * 32 + d] = acc[i][j];
        }
    }
}

// ---------------- RoPE in place on Q and K ----------------
__global__ void rope_k(float* __restrict__ Q, float* __restrict__ Kq,
                       const float* __restrict__ ct, const float* __restrict__ st) {
    int id = blockIdx.x * 256 + threadIdx.x;  // 32*2048*16
    if (id >= 32 * 2048 * 16) return;
    int i = id & 15;
    int s = (id >> 4) & 2047;
    int bh = id >> 15;
    int base = (bh * 2048 + s) * 32 + 2 * i;
    int j0 = (2 * i) & 15;
    float c0 = ct[s * 16 + j0], s0 = st[s * 16 + j0];
    float c1 = ct[s * 16 + j0 + 1], s1 = st[s * 16 + j0 + 1];
    float2 q = *(float2*)&Q[base];
    float2 k = *(float2*)&Kq[base];
    float2 qo, ko;
    qo.x = q.x * c0 - q.y * s0;
    qo.y = q.y * c1 + q.x * s1;
    ko.x = k.x * c0 - k.y * s0;
    ko.y = k.y * c1 + k.x * s1;
    *(float2*)&Q[base] = qo;
    *(float2*)&Kq[base] = ko;
}

// ---------------- Flash attention: 1 query row per thread, KT=64 tiles ----------------
__global__ __launch_bounds__(256) void attn_k(const float* __restrict__ Q,
                                              const float* __restrict__ Kg,
                                              const float* __restrict__ Vg,
                                              float* __restrict__ ctx) {
    __shared__ float4 Kl[64][8];
    __shared__ float4 Vl[64][8];
    int bh = blockIdx.x, qt = blockIdx.y;
    int t = threadIdx.x;
    int row = qt * 256 + t;
    const float4* Qb = (const float4*)(Q + (size_t)bh * 2048 * 32);
    const float4* Kb = (const float4*)(Kg + (size_t)bh * 2048 * 32);
    const float4* Vb = (const float4*)(Vg + (size_t)bh * 2048 * 32);
    float4 q4[8];
#pragma unroll
    for (int d = 0; d < 8; d++) q4[d] = Qb[row * 8 + d];
    float4 o4[8] = {};
    float m = -1e30f, l = 0.f;
    const float scale = 0.17677669529663687f;  // 1/sqrt(32)
    int ntile = (qt + 1) * 4;
    int skey = t >> 2, sdq = (t & 3) * 2;
    for (int kt = 0; kt < ntile; kt++) {
        int kbase = kt * 64;
        Kl[skey][sdq] = Kb[(kbase + skey) * 8 + sdq];
        Kl[skey][sdq + 1] = Kb[(kbase + skey) * 8 + sdq + 1];
        Vl[skey][sdq] = Vb[(kbase + skey) * 8 + sdq];
        Vl[skey][sdq + 1] = Vb[(kbase + skey) * 8 + sdq + 1];
        __syncthreads();
        int jmax = row - kbase + 1;
        if (jmax > 64) jmax = 64;
        for (int j = 0; j < jmax; j++) {
            float s = 0.f;
#pragma unroll
            for (int d = 0; d < 8; d++) {
                float4 k4 = Kl[j][d];
                s += q4[d].x * k4.x + q4[d].y * k4.y + q4[d].z * k4.z + q4[d].w * k4.w;
            }
            s *= scale;
            if (s > m) {
                float r = __expf(m - s);
#pragma unroll
                for (int d = 0; d < 8; d++) {
                    o4[d].x *= r; o4[d].y *= r; o4[d].z *= r; o4[d].w *= r;
                }
                l *= r;
                m = s;
            }
            float p = __expf(s - m);
            l += p;
#pragma unroll
            for (int d = 0; d < 8; d++) {
                float4 v4 = Vl[j][d];
                o4[d].x += p * v4.x; o4[d].y += p * v4.y;
                o4[d].z += p * v4.z; o4[d].w += p * v4.w;
            }
        }
        __syncthreads();
    }
    float invl = 1.f / l;
    int b = bh >> 3, h = bh & 7;
    float4* cp = (float4*)(ctx + ((size_t)(b * 2048 + row)) * 256 + h * 32);
#pragma unroll
    for (int d = 0; d < 8; d++) {
        float4 v = o4[d];
        v.x *= invl; v.y *= invl; v.z *= invl; v.w *= invl;
        cp[d] = v;
    }
}

// ---------------- out projection + residual: x2 = ctx@Wout + x ----------------
__global__ __launch_bounds__(256) void gemm_out(const float* __restrict__ A,
                                                const float* __restrict__ W,
                                                const float* __restrict__ xres,
                                                float* __restrict__ x2) {
    __shared__ float As[16][64];
    __shared__ float Bs[16][64];
    int t = threadIdx.x;
    int m0 = blockIdx.y * 64, n0 = blockIdx.x * 64;
    float acc[4][4] = {};
    int am = t >> 2, ak = (t & 3) * 4;
    int bk = t >> 4, bn = (t & 15) * 4;
    int tm = (t & 15) * 4, tn = (t >> 4) * 4;
    for (int k0 = 0; k0 < 256; k0 += 16) {
        float4 av = *(const float4*)&A[(m0 + am) * 256 + k0 + ak];
        As[ak + 0][am] = av.x; As[ak + 1][am] = av.y; As[ak + 2][am] = av.z; As[ak + 3][am] = av.w;
        float4 bv = *(const float4*)&W[(k0 + bk) * 256 + n0 + bn];
        *(float4*)&Bs[bk][bn] = bv;
        __syncthreads();
#pragma unroll
        for (int kk = 0; kk < 16; kk++) {
            float4 a4 = *(float4*)&As[kk][tm];
            float4 b4 = *(float4*)&Bs[kk][tn];
            float a[4] = {a4.x, a4.y, a4.z, a4.w};
            float b[4] = {b4.x, b4.y, b4.z, b4.w};
#pragma unroll
            for (int i = 0; i < 4; i++)
#pragma unroll
                for (int j = 0; j < 4; j++) acc[i][j] += a[i] * b[j];
        }
        __syncthreads();
    }
#pragma unroll
    for (int i = 0; i < 4; i++) {
        int rowi = m0 + tm + i;
#pragma unroll
        for (int j = 0; j < 4; j++) {
            int c = n0 + tn + j;
            x2[rowi * 256 + c] = acc[i][j] + xres[rowi * 256 + c];
        }
    }
}

// ---------------- gate: logits, softmax, top-2, importance/counts ----------------
__global__ void gate_k(const float* __restrict__ xn2, const float* __restrict__ gw,
                       int* __restrict__ idx, float* __restrict__ wts,
                       int* __restrict__ cnt, float* __restrict__ imp) {
    __shared__ float simp[NE];
    __shared__ int scnt[NE];
    int t = threadIdx.x;
    int n = blockIdx.x * 256 + t;
    if (t < NE) { simp[t] = 0.f; scnt[t] = 0; }
    __syncthreads();
    float lg[NE] = {0, 0, 0, 0, 0, 0};
    for (int k = 0; k < 256; k++) {
        float xv = xn2[n * 256 + k];
#pragma unroll
        for (int e = 0; e < NE; e++) lg[e] += xv * gw[k * NE + e];
    }
    float mx = lg[0];
#pragma unroll
    for (int e = 1; e < NE; e++) mx = fmaxf(mx, lg[e]);
    float p[NE], se = 0.f;
#pragma unroll
    for (int e = 0; e < NE; e++) { p[e] = expf(lg[e] - mx); se += p[e]; }
    float inv = 1.f / se;
#pragma unroll
    for (int e = 0; e < NE; e++) p[e] *= inv;
    int i1 = 0; float v1 = p[0];
#pragma unroll
    for (int e = 1; e < NE; e++) if (p[e] > v1) { v1 = p[e]; i1 = e; }
    int i2 = -1; float v2 = -1.f;
#pragma unroll
    for (int e = 0; e < NE; e++) if (e != i1 && p[e] > v2) { v2 = p[e]; i2 = e; }
    float e2v = expf(v2 - v1);
    float w1 = 1.f / (1.f + e2v);
    float w2 = e2v / (1.f + e2v);
    idx[n * 2] = i1; idx[n * 2 + 1] = i2;
    wts[n * 2] = w1; wts[n * 2 + 1] = w2;
#pragma unroll
    for (int e = 0; e < NE; e++) atomicAdd(&simp[e], p[e]);
    atomicAdd(&scnt[i1], 1);
    atomicAdd(&scnt[i2], 1);
    __syncthreads();
    if (t < NE) {
        atomicAdd(&imp[t], simp[t]);
        atomicAdd(&cnt[t], scnt[t]);
    }
}

// ---------------- prefix sums + aux loss ----------------
__global__ void prefix_k(const int* __restrict__ cnt, const float* __restrict__ imp,
                         int* __restrict__ offs, int* __restrict__ cur,
                         float* __restrict__ auxout) {
    if (threadIdx.x == 0) {
        int o = 0;
        float a = 0.f;
        for (int e = 0; e < NE; e++) {
            offs[e] = o;
            cur[e] = o;
            o += cnt[e];
            a += imp[e] * (float)cnt[e];
        }
        auxout[0] = 6.0f * a / (8192.0f * 8192.0f);
    }
}

// ---------------- scatter token slots into expert buckets ----------------
__global__ void scatter_k(const int* __restrict__ idx, int* __restrict__ cur,
                          int* __restrict__ ltok, int* __restrict__ slotp) {
    int n = blockIdx.x * 256 + threadIdx.x;
#pragma unroll
    for (int s = 0; s < 2; s++) {
        int e = idx[n * 2 + s];
        int pos = atomicAdd(&cur[e], 1);
        ltok[pos] = n;
        slotp[n * 2 + s] = pos;
    }
}

// ---------------- expert GEMM 1: H = silu(A@Wg)*(A@Wu), gathered rows ----------------
__global__ __launch_bounds__(256) void moe_gemm1(const float* __restrict__ xn2,
                                                 const float* __restrict__ Wg,
                                                 const float* __restrict__ Wu,
                                                 const int* __restrict__ cnt,
                                                 const int* __restrict__ offs,
                                                 const int* __restrict__ ltok,
                                                 __hip_bfloat16* __restrict__ Hbuf) {
    int e = blockIdx.z;
    int Me = cnt[e];
    int m0 = blockIdx.y * 64;
    if (m0 >= Me) return;
    int off = offs[e];
    __shared__ float As[16][64];
    __shared__ float Bg[16][64];
    __shared__ float Bu[16][64];
    __shared__ int stok[64];
    int t = threadIdx.x;
    if (t < 64) stok[t] = (m0 + t < Me) ? ltok[off + m0 + t] : 0;
    __syncthreads();
    const float* WgE = Wg + (size_t)e * 256 * 768;
    const float* WuE = Wu + (size_t)e * 256 * 768;
    int n0 = blockIdx.x * 64;
    float accG[4][4] = {}, accU[4][4] = {};
    int am = t >> 2, ak = (t & 3) * 4;
    int bk = t >> 4, bn = (t & 15) * 4;
    int tm = (t & 15) * 4, tn = (t >> 4) * 4;
    for (int k0 = 0; k0 < 256; k0 += 16) {
        float4 av = *(const float4*)&xn2[stok[am] * 256 + k0 + ak];
        As[ak + 0][am] = av.x; As[ak + 1][am] = av.y; As[ak + 2][am] = av.z; As[ak + 3][am] = av.w;
        float4 g4 = *(const float4*)&WgE[(k0 + bk) * 768 + n0 + bn];
        *(float4*)&Bg[bk][bn] = g4;
        float4 u4 = *(const float4*)&WuE[(k0 + bk) * 768 + n0 + bn];
        *(float4*)&Bu[bk][bn] = u4;
        __syncthreads();
#pragma unroll
        for (int kk = 0; kk < 16; kk++) {
            float4 a4 = *(float4*)&As[kk][tm];
            float4 g4 = *(float4*)&Bg[kk][tn];
            float4 u4 = *(float4*)&Bu[kk][tn];
            float a[4] = {a4.x, a4.y, a4.z, a4.w};
            float g[4] = {g4.x, g4.y, g4.z, g4.w};
            float u[4] = {u4.x, u4.y, u4.z, u4.w};
#pragma unroll
            for (int i = 0; i < 4; i++)
#pragma unroll
                for (int j = 0; j < 4; j++) {
                    accG[i][j] += a[i] * g[j];
                    accU[i][j] += a[i] * u[j];
                }
        }
        __syncthreads();
    }
#pragma unroll
    for (int i = 0; i < 4; i++) {
        int m = m0 + tm + i;
        if (m < Me) {
            size_t rp = (size_t)(off + m) * 768;
#pragma unroll
            for (int j = 0; j < 4; j++) {
                float g = accG[i][j], u = accU[i][j];
                float hv = g / (1.f + expf(-g)) * u;
                Hbuf[rp + n0 + tn + j] = __float2bfloat16(hv);
            }
        }
    }
}

// ---------------- expert GEMM 2: Y = H @ Wd ----------------
__global__ __launch_bounds__(256) void moe_gemm2(const __hip_bfloat16* __restrict__ Hbuf,
                                                 const float* __restrict__ Wd,
                                                 const int* __restrict__ cnt,
                                                 const int* __restrict__ offs,
                                                 __hip_bfloat16* __restrict__ Y) {
    int e = blockIdx.z;
    int Me = cnt[e];
    int m0 = blockIdx.y * 64;
    if (m0 >= Me) return;
    int off = offs[e];
    __shared__ float As[16][64];
    __shared__ float Bs[16][64];
    int t = threadIdx.x;
    int am = t >> 2, ak = (t & 3) * 4;
    int bk = t >> 4, bn = (t & 15) * 4;
    int tm = (t & 15) * 4, tn = (t >> 4) * 4;
    const float* WdE = Wd + (size_t)e * 768 * 256;
    int n0 = blockIdx.x * 64;
    float acc[4][4] = {};
    int arow = off + min(m0 + am, Me - 1);
    for (int k0 = 0; k0 < 768; k0 += 16) {
        const __hip_bfloat16* hp = &Hbuf[(size_t)arow * 768 + k0 + ak];
        As[ak + 0][am] = __bfloat162float(hp[0]);
        As[ak + 1][am] = __bfloat162float(hp[1]);
        As[ak + 2][am] = __bfloat162float(hp[2]);
        As[ak + 3][am] = __bfloat162float(hp[3]);
        float4 bv = *(const float4*)&WdE[(k0 + bk) * 256 + n0 + bn];
        *(float4*)&Bs[bk][bn] = bv;
        __syncthreads();
#pragma unroll
        for (int kk = 0; kk < 16; kk++) {
            float4 a4 = *(float4*)&As[kk][tm];
            float4 b4 = *(float4*)&Bs[kk][tn];
            float a[4] = {a4.x, a4.y, a4.z, a4.w};
            float b[4] = {b4.x, b4.y, b4.z, b4.w};
#pragma unroll
            for (int i = 0; i < 4; i++)
#pragma unroll
                for (int j = 0; j < 4; j++) acc[i][j] += a[i] * b[j];
        }
        __syncthreads();
    }
#pragma unroll
    for (int i = 0; i < 4; i++) {
        int m = m0 + tm + i;
        if (m < Me) {
            size_t rp = (size_t)(off + m) * 256;
#pragma unroll
            for (int j = 0; j < 4; j++)
                Y[rp + n0 + tn + j] = __float2bfloat16(acc[i][j]);
        }
    }
}

// ---------------- final combine: out = x2 + w0*Y[p0] + w1*Y[p1] ----------------
__global__ void combine_k(const float* __restrict__ x2, const __hip_bfloat16* __restrict__ Y,
                          const int* __restrict__ slotp, const float* __restrict__ wts,
                          float* __restrict__ out) {
    int n = blockIdx.x, t = threadIdx.x;
    int p0 = slotp[n * 2], p1 = slotp[n * 2 + 1];
    float w0 = wts[n * 2], w1 = wts[n * 2 + 1];
    out[n * 256 + t] = x2[n * 256 + t] + w0 * __bfloat162float(Y[(size_t)p0 * 256 + t]) +
                       w1 * __bfloat162float(Y[(size_t)p1 * 256 + t]);
}

extern "C" void kernel_launch(void* const* d_in, const int* in_sizes, int n_in,
                              void* d_out, int out_size, void* d_ws, size_t ws_size,
                              hipStream_t stream) {
    const float* x     = (const float*)d_in[0];
    const float* Wqkv  = (const float*)d_in[1];
    const float* Wout  = (const float*)d_in[2];
    const float* rms1w = (const float*)d_in[3];
    const float* rms2w = (const float*)d_in[4];
    const float* gateW = (const float*)d_in[5];
    const float* Wg    = (const float*)d_in[6];
    const float* Wu    = (const float*)d_in[7];
    const float* Wd    = (const float*)d_in[8];
    float* out = (float*)d_out;
    char* ws = (char*)d_ws;

    float* xn1 = (float*)(ws + 0);
    float* Qb  = (float*)(ws + 8388608);
    float* Kb  = (float*)(ws + 16777216);
    float* Vb  = (float*)(ws + 25165824);
    float* ctx = (float*)(ws + 33554432);
    __hip_bfloat16* Hbuf = (__hip_bfloat16*)(ws + 0);         // reuses xn1/Q/K (dead)
    __hip_bfloat16* Ybuf = (__hip_bfloat16*)(ws + 25165824);  // reuses V (dead)
    float* x2  = (float*)(ws + 41943040);
    float* xn2 = (float*)(ws + 50331648);
    float* ct  = (float*)(ws + 58720256);
    float* st  = (float*)(ws + 58851328);
    int*   idx = (int*)(ws + 58982400);
    float* wts = (float*)(ws + 59047936);
    int* slotp = (int*)(ws + 59113472);
    int* ltok  = (int*)(ws + 59179008);
    int* cnt   = (int*)(ws + 59244544);
    int* offs  = cnt + 8;
    int* cur   = cnt + 16;
    float* imp = (float*)(cnt + 24);

    hipMemsetAsync(cnt, 0, 128, stream);

    rope_tables<<<128, 256, 0, stream>>>(ct, st);
    rmsnorm_k<<<8192, 256, 0, stream>>>(x, rms1w, xn1);
    gemm_qkv<<<dim3(12, 128), 256, 0, stream>>>(xn1, Wqkv, Qb, Kb, Vb);
    rope_k<<<4096, 256, 0, stream>>>(Qb, Kb, ct, st);
    attn_k<<<dim3(32, 8), 256, 0, stream>>>(Qb, Kb, Vb, ctx);
    gemm_out<<<dim3(4, 128), 256, 0, stream>>>(ctx, Wout, x, x2);
    rmsnorm_k<<<8192, 256, 0, stream>>>(x2, rms2w, xn2);
    gate_k<<<32, 256, 0, stream>>>(xn2, gateW, idx, wts, cnt, imp);
    prefix_k<<<1, 64, 0, stream>>>(cnt, imp, offs, cur, out + 2097152);
    scatter_k<<<32, 256, 0, stream>>>(idx, cur, ltok, slotp);
    moe_gemm1<<<dim3(12, 128, NE), 256, 0, stream>>>(xn2, Wg, Wu, cnt, offs, ltok, Hbuf);
    moe_gemm2<<<dim3(4, 128, NE), 256, 0, stream>>>(Hbuf, Wd, cnt, offs, Ybuf);
    combine_k<<<8192, 256, 0, stream>>>(x2, Ybuf, slotp, wts, out);
}

// Round 3
// 944.939 us; speedup vs baseline: 1.3092x; 1.3092x over previous
//
#include <hip/hip_runtime.h>
#include <hip/hip_bf16.h>
#include <math.h>

#define NE 6

// ---------------- RoPE tables ----------------
__global__ void rope_tables(float* __restrict__ ct, float* __restrict__ st) {
    int id = blockIdx.x * 256 + threadIdx.x;   // 2048*16
    if (id >= 2048 * 16) return;
    int s = id >> 4, f = id & 15;
    float invf = expf(-logf(10000.0f) * (float)f / 16.0f);
    float ang = (float)s * invf;
    ct[id] = cosf(ang);
    st[id] = sinf(ang);
}

// ---------------- RMSNorm ----------------
__global__ void rmsnorm_k(const float* __restrict__ x, const float* __restrict__ w,
                          float* __restrict__ o) {
    __shared__ float red[256];
    int n = blockIdx.x, t = threadIdx.x;
    float v = x[n * 256 + t];
    red[t] = v * v;
    __syncthreads();
    for (int s = 128; s > 0; s >>= 1) {
        if (t < s) red[t] += red[t + s];
        __syncthreads();
    }
    float rms = rsqrtf(red[0] / 256.0f + 1e-6f);
    o[n * 256 + t] = v * rms * w[t];
}

// ---------------- QKV GEMM: (8192x256)@(256x768), scatter to Q/K/V (B,H,S,D) ----------------
__global__ __launch_bounds__(256) void gemm_qkv(const float* __restrict__ A,
                                                const float* __restrict__ W,
                                                float* __restrict__ Q, float* __restrict__ Kq,
                                                float* __restrict__ V) {
    __shared__ float As[16][64];
    __shared__ float Bs[16][64];
    int t = threadIdx.x;
    int m0 = blockIdx.y * 64, n0 = blockIdx.x * 64;
    float acc[4][4] = {};
    int am = t >> 2, ak = (t & 3) * 4;
    int bk = t >> 4, bn = (t & 15) * 4;
    int tm = (t & 15) * 4, tn = (t >> 4) * 4;
    for (int k0 = 0; k0 < 256; k0 += 16) {
        float4 av = *(const float4*)&A[(m0 + am) * 256 + k0 + ak];
        As[ak + 0][am] = av.x; As[ak + 1][am] = av.y; As[ak + 2][am] = av.z; As[ak + 3][am] = av.w;
        float4 bv = *(const float4*)&W[(k0 + bk) * 768 + n0 + bn];
        *(float4*)&Bs[bk][bn] = bv;
        __syncthreads();
#pragma unroll
        for (int kk = 0; kk < 16; kk++) {
            float4 a4 = *(float4*)&As[kk][tm];
            float4 b4 = *(float4*)&Bs[kk][tn];
            float a[4] = {a4.x, a4.y, a4.z, a4.w};
            float b[4] = {b4.x, b4.y, b4.z, b4.w};
#pragma unroll
            for (int i = 0; i < 4; i++)
#pragma unroll
                for (int j = 0; j < 4; j++) acc[i][j] += a[i] * b[j];
        }
        __syncthreads();
    }
    int part = n0 >> 8;
    float* dst = part == 0 ? Q : (part == 1 ? Kq : V);
#pragma unroll
    for (int i = 0; i < 4; i++) {
        int rowi = m0 + tm + i;
        int b = rowi >> 11, s = rowi & 2047;
#pragma unroll
        for (int j = 0; j < 4; j++) {
            int c = n0 + tn + j;
            int e = c & 255, h = e >> 5, d = e & 31;
            dst[(((size_t)(b * 8 + h)) * 2048 + s) * 32 + d] = acc[i][j];
        }
    }
}

// ---------------- RoPE in place on Q and K ----------------
__global__ void rope_k(float* __restrict__ Q, float* __restrict__ Kq,
                       const float* __restrict__ ct, const float* __restrict__ st) {
    int id = blockIdx.x * 256 + threadIdx.x;  // 32*2048*16
    if (id >= 32 * 2048 * 16) return;
    int i = id & 15;
    int s = (id >> 4) & 2047;
    int bh = id >> 15;
    int base = (bh * 2048 + s) * 32 + 2 * i;
    int j0 = (2 * i) & 15;
    float c0 = ct[s * 16 + j0], s0 = st[s * 16 + j0];
    float c1 = ct[s * 16 + j0 + 1], s1 = st[s * 16 + j0 + 1];
    float2 q = *(float2*)&Q[base];
    float2 k = *(float2*)&Kq[base];
    float2 qo, ko;
    qo.x = q.x * c0 - q.y * s0;
    qo.y = q.y * c1 + q.x * s1;
    ko.x = k.x * c0 - k.y * s0;
    ko.y = k.y * c1 + k.x * s1;
    *(float2*)&Q[base] = qo;
    *(float2*)&Kq[base] = ko;
}

// ---------------- Flash attention: 4 lanes per query row, 64 rows/block ----------------
__global__ __launch_bounds__(256) void attn_k(const float* __restrict__ Q,
                                              const float* __restrict__ Kg,
                                              const float* __restrict__ Vg,
                                              float* __restrict__ ctx) {
    __shared__ float4 Kl[64][8];
    __shared__ float4 Vl[64][8];
    int bh = blockIdx.x;
    int qt = gridDim.y - 1 - blockIdx.y;   // longest blocks launch first
    int t = threadIdx.x;
    int sub = t & 3;          // which 8-dim slice of D
    int row = qt * 64 + (t >> 2);
    const float4* Qb = (const float4*)(Q + (size_t)bh * 2048 * 32);
    const float4* Kb = (const float4*)(Kg + (size_t)bh * 2048 * 32);
    const float4* Vb = (const float4*)(Vg + (size_t)bh * 2048 * 32);
    float4 q0 = Qb[row * 8 + sub * 2];
    float4 q1 = Qb[row * 8 + sub * 2 + 1];
    float4 o0 = {}, o1 = {};
    float m = -1e30f, l = 0.f;
    const float scale = 0.17677669529663687f;  // 1/sqrt(32)
    int ntile = qt + 1;
    float4* Klf = &Kl[0][0];
    float4* Vlf = &Vl[0][0];
    for (int kt = 0; kt < ntile; kt++) {
        int kbase = kt * 64;
        Klf[t] = Kb[kbase * 8 + t];
        Klf[t + 256] = Kb[kbase * 8 + t + 256];
        Vlf[t] = Vb[kbase * 8 + t];
        Vlf[t + 256] = Vb[kbase * 8 + t + 256];
        __syncthreads();
        int jmax = row - kbase + 1;
        if (jmax > 64) jmax = 64;
        for (int j = 0; j < jmax; j++) {
            float4 k0 = Kl[j][sub * 2];
            float4 k1 = Kl[j][sub * 2 + 1];
            float s = q0.x * k0.x + q0.y * k0.y + q0.z * k0.z + q0.w * k0.w +
                      q1.x * k1.x + q1.y * k1.y + q1.z * k1.z + q1.w * k1.w;
            s += __shfl_xor(s, 1);
            s += __shfl_xor(s, 2);
            s *= scale;
            if (s > m) {
                float r = __expf(m - s);
                o0.x *= r; o0.y *= r; o0.z *= r; o0.w *= r;
                o1.x *= r; o1.y *= r; o1.z *= r; o1.w *= r;
                l *= r;
                m = s;
            }
            float p = __expf(s - m);
            l += p;
            float4 v0 = Vl[j][sub * 2];
            float4 v1 = Vl[j][sub * 2 + 1];
            o0.x += p * v0.x; o0.y += p * v0.y; o0.z += p * v0.z; o0.w += p * v0.w;
            o1.x += p * v1.x; o1.y += p * v1.y; o1.z += p * v1.z; o1.w += p * v1.w;
        }
        __syncthreads();
    }
    float invl = 1.f / l;
    int b = bh >> 3, h = bh & 7;
    float4* cp = (float4*)(ctx + ((size_t)(b * 2048 + row)) * 256 + h * 32 + sub * 8);
    o0.x *= invl; o0.y *= invl; o0.z *= invl; o0.w *= invl;
    o1.x *= invl; o1.y *= invl; o1.z *= invl; o1.w *= invl;
    cp[0] = o0;
    cp[1] = o1;
}

// ---------------- out projection + residual: x2 = ctx@Wout + x ----------------
__global__ __launch_bounds__(256) void gemm_out(const float* __restrict__ A,
                                                const float* __restrict__ W,
                                                const float* __restrict__ xres,
                                                float* __restrict__ x2) {
    __shared__ float As[16][64];
    __shared__ float Bs[16][64];
    int t = threadIdx.x;
    int m0 = blockIdx.y * 64, n0 = blockIdx.x * 64;
    float acc[4][4] = {};
    int am = t >> 2, ak = (t & 3) * 4;
    int bk = t >> 4, bn = (t & 15) * 4;
    int tm = (t & 15) * 4, tn = (t >> 4) * 4;
    for (int k0 = 0; k0 < 256; k0 += 16) {
        float4 av = *(const float4*)&A[(m0 + am) * 256 + k0 + ak];
        As[ak + 0][am] = av.x; As[ak + 1][am] = av.y; As[ak + 2][am] = av.z; As[ak + 3][am] = av.w;
        float4 bv = *(const float4*)&W[(k0 + bk) * 256 + n0 + bn];
        *(float4*)&Bs[bk][bn] = bv;
        __syncthreads();
#pragma unroll
        for (int kk = 0; kk < 16; kk++) {
            float4 a4 = *(float4*)&As[kk][tm];
            float4 b4 = *(float4*)&Bs[kk][tn];
            float a[4] = {a4.x, a4.y, a4.z, a4.w};
            float b[4] = {b4.x, b4.y, b4.z, b4.w};
#pragma unroll
            for (int i = 0; i < 4; i++)
#pragma unroll
                for (int j = 0; j < 4; j++) acc[i][j] += a[i] * b[j];
        }
        __syncthreads();
    }
#pragma unroll
    for (int i = 0; i < 4; i++) {
        int rowi = m0 + tm + i;
#pragma unroll
        for (int j = 0; j < 4; j++) {
            int c = n0 + tn + j;
            x2[rowi * 256 + c] = acc[i][j] + xres[rowi * 256 + c];
        }
    }
}

// ---------------- gate: logits, softmax, top-2, importance/counts ----------------
__global__ void gate_k(const float* __restrict__ xn2, const float* __restrict__ gw,
                       int* __restrict__ idx, float* __restrict__ wts,
                       int* __restrict__ cnt, float* __restrict__ imp) {
    __shared__ float simp[NE];
    __shared__ int scnt[NE];
    int t = threadIdx.x;
    int n = blockIdx.x * 256 + t;
    if (t < NE) { simp[t] = 0.f; scnt[t] = 0; }
    __syncthreads();
    float lg[NE] = {0, 0, 0, 0, 0, 0};
    for (int k = 0; k < 256; k++) {
        float xv = xn2[n * 256 + k];
#pragma unroll
        for (int e = 0; e < NE; e++) lg[e] += xv * gw[k * NE + e];
    }
    float mx = lg[0];
#pragma unroll
    for (int e = 1; e < NE; e++) mx = fmaxf(mx, lg[e]);
    float p[NE], se = 0.f;
#pragma unroll
    for (int e = 0; e < NE; e++) { p[e] = expf(lg[e] - mx); se += p[e]; }
    float inv = 1.f / se;
#pragma unroll
    for (int e = 0; e < NE; e++) p[e] *= inv;
    int i1 = 0; float v1 = p[0];
#pragma unroll
    for (int e = 1; e < NE; e++) if (p[e] > v1) { v1 = p[e]; i1 = e; }
    int i2 = -1; float v2 = -1.f;
#pragma unroll
    for (int e = 0; e < NE; e++) if (e != i1 && p[e] > v2) { v2 = p[e]; i2 = e; }
    float e2v = expf(v2 - v1);
    float w1 = 1.f / (1.f + e2v);
    float w2 = e2v / (1.f + e2v);
    idx[n * 2] = i1; idx[n * 2 + 1] = i2;
    wts[n * 2] = w1; wts[n * 2 + 1] = w2;
#pragma unroll
    for (int e = 0; e < NE; e++) atomicAdd(&simp[e], p[e]);
    atomicAdd(&scnt[i1], 1);
    atomicAdd(&scnt[i2], 1);
    __syncthreads();
    if (t < NE) {
        atomicAdd(&imp[t], simp[t]);
        atomicAdd(&cnt[t], scnt[t]);
    }
}

// ---------------- prefix sums + aux loss ----------------
__global__ void prefix_k(const int* __restrict__ cnt, const float* __restrict__ imp,
                         int* __restrict__ offs, int* __restrict__ cur,
                         float* __restrict__ auxout) {
    if (threadIdx.x == 0) {
        int o = 0;
        float a = 0.f;
        for (int e = 0; e < NE; e++) {
            offs[e] = o;
            cur[e] = o;
            o += cnt[e];
            a += imp[e] * (float)cnt[e];
        }
        auxout[0] = 6.0f * a / (8192.0f * 8192.0f);
    }
}

// ---------------- scatter token slots into expert buckets ----------------
__global__ void scatter_k(const int* __restrict__ idx, int* __restrict__ cur,
                          int* __restrict__ ltok, int* __restrict__ slotp) {
    int n = blockIdx.x * 256 + threadIdx.x;
#pragma unroll
    for (int s = 0; s < 2; s++) {
        int e = idx[n * 2 + s];
        int pos = atomicAdd(&cur[e], 1);
        ltok[pos] = n;
        slotp[n * 2 + s] = pos;
    }
}

// ---------------- expert GEMM 1: H = silu(A@Wg)*(A@Wu), gathered rows ----------------
__global__ __launch_bounds__(256) void moe_gemm1(const float* __restrict__ xn2,
                                                 const float* __restrict__ Wg,
                                                 const float* __restrict__ Wu,
                                                 const int* __restrict__ cnt,
                                                 const int* __restrict__ offs,
                                                 const int* __restrict__ ltok,
                                                 __hip_bfloat16* __restrict__ Hbuf) {
    int e = blockIdx.z;
    int Me = cnt[e];
    int m0 = blockIdx.y * 64;
    if (m0 >= Me) return;
    int off = offs[e];
    __shared__ float As[16][64];
    __shared__ float Bg[16][64];
    __shared__ float Bu[16][64];
    __shared__ int stok[64];
    int t = threadIdx.x;
    if (t < 64) stok[t] = (m0 + t < Me) ? ltok[off + m0 + t] : 0;
    __syncthreads();
    const float* WgE = Wg + (size_t)e * 256 * 768;
    const float* WuE = Wu + (size_t)e * 256 * 768;
    int n0 = blockIdx.x * 64;
    float accG[4][4] = {}, accU[4][4] = {};
    int am = t >> 2, ak = (t & 3) * 4;
    int bk = t >> 4, bn = (t & 15) * 4;
    int tm = (t & 15) * 4, tn = (t >> 4) * 4;
    for (int k0 = 0; k0 < 256; k0 += 16) {
        float4 av = *(const float4*)&xn2[stok[am] * 256 + k0 + ak];
        As[ak + 0][am] = av.x; As[ak + 1][am] = av.y; As[ak + 2][am] = av.z; As[ak + 3][am] = av.w;
        float4 g4 = *(const float4*)&WgE[(k0 + bk) * 768 + n0 + bn];
        *(float4*)&Bg[bk][bn] = g4;
        float4 u4 = *(const float4*)&WuE[(k0 + bk) * 768 + n0 + bn];
        *(float4*)&Bu[bk][bn] = u4;
        __syncthreads();
#pragma unroll
        for (int kk = 0; kk < 16; kk++) {
            float4 a4 = *(float4*)&As[kk][tm];
            float4 g4 = *(float4*)&Bg[kk][tn];
            float4 u4 = *(float4*)&Bu[kk][tn];
            float a[4] = {a4.x, a4.y, a4.z, a4.w};
            float g[4] = {g4.x, g4.y, g4.z, g4.w};
            float u[4] = {u4.x, u4.y, u4.z, u4.w};
#pragma unroll
            for (int i = 0; i < 4; i++)
#pragma unroll
                for (int j = 0; j < 4; j++) {
                    accG[i][j] += a[i] * g[j];
                    accU[i][j] += a[i] * u[j];
                }
        }
        __syncthreads();
    }
#pragma unroll
    for (int i = 0; i < 4; i++) {
        int m = m0 + tm + i;
        if (m < Me) {
            size_t rp = (size_t)(off + m) * 768;
#pragma unroll
            for (int j = 0; j < 4; j++) {
                float g = accG[i][j], u = accU[i][j];
                float hv = g / (1.f + expf(-g)) * u;
                Hbuf[rp + n0 + tn + j] = __float2bfloat16(hv);
            }
        }
    }
}

// ---------------- expert GEMM 2: Y = H @ Wd ----------------
__global__ __launch_bounds__(256) void moe_gemm2(const __hip_bfloat16* __restrict__ Hbuf,
                                                 const float* __restrict__ Wd,
                                                 const int* __restrict__ cnt,
                                                 const int* __restrict__ offs,
                                                 __hip_bfloat16* __restrict__ Y) {
    int e = blockIdx.z;
    int Me = cnt[e];
    int m0 = blockIdx.y * 64;
    if (m0 >= Me) return;
    int off = offs[e];
    __shared__ float As[16][64];
    __shared__ float Bs[16][64];
    int t = threadIdx.x;
    int am = t >> 2, ak = (t & 3) * 4;
    int bk = t >> 4, bn = (t & 15) * 4;
    int tm = (t & 15) * 4, tn = (t >> 4) * 4;
    const float* WdE = Wd + (size_t)e * 768 * 256;
    int n0 = blockIdx.x * 64;
    float acc[4][4] = {};
    int arow = off + min(m0 + am, Me - 1);
    for (int k0 = 0; k0 < 768; k0 += 16) {
        const __hip_bfloat16* hp = &Hbuf[(size_t)arow * 768 + k0 + ak];
        As[ak + 0][am] = __bfloat162float(hp[0]);
        As[ak + 1][am] = __bfloat162float(hp[1]);
        As[ak + 2][am] = __bfloat162float(hp[2]);
        As[ak + 3][am] = __bfloat162float(hp[3]);
        float4 bv = *(const float4*)&WdE[(k0 + bk) * 256 + n0 + bn];
        *(float4*)&Bs[bk][bn] = bv;
        __syncthreads();
#pragma unroll
        for (int kk = 0; kk < 16; kk++) {
            float4 a4 = *(float4*)&As[kk][tm];
            float4 b4 = *(float4*)&Bs[kk][tn];
            float a[4] = {a4.x, a4.y, a4.z, a4.w};
            float b[4] = {b4.x, b4.y, b4.z, b4.w};
#pragma unroll
            for (int i = 0; i < 4; i++)
#pragma unroll
                for (int j = 0; j < 4; j++) acc[i][j] += a[i] * b[j];
        }
        __syncthreads();
    }
#pragma unroll
    for (int i = 0; i < 4; i++) {
        int m = m0 + tm + i;
        if (m < Me) {
            size_t rp = (size_t)(off + m) * 256;
#pragma unroll
            for (int j = 0; j < 4; j++)
                Y[rp + n0 + tn + j] = __float2bfloat16(acc[i][j]);
        }
    }
}

// ---------------- final combine: out = x2 + w0*Y[p0] + w1*Y[p1] ----------------
__global__ void combine_k(const float* __restrict__ x2, const __hip_bfloat16* __restrict__ Y,
                          const int* __restrict__ slotp, const float* __restrict__ wts,
                          float* __restrict__ out) {
    int n = blockIdx.x, t = threadIdx.x;
    int p0 = slotp[n * 2], p1 = slotp[n * 2 + 1];
    float w0 = wts[n * 2], w1 = wts[n * 2 + 1];
    out[n * 256 + t] = x2[n * 256 + t] + w0 * __bfloat162float(Y[(size_t)p0 * 256 + t]) +
                       w1 * __bfloat162float(Y[(size_t)p1 * 256 + t]);
}

extern "C" void kernel_launch(void* const* d_in, const int* in_sizes, int n_in,
                              void* d_out, int out_size, void* d_ws, size_t ws_size,
                              hipStream_t stream) {
    const float* x     = (const float*)d_in[0];
    const float* Wqkv  = (const float*)d_in[1];
    const float* Wout  = (const float*)d_in[2];
    const float* rms1w = (const float*)d_in[3];
    const float* rms2w = (const float*)d_in[4];
    const float* gateW = (const float*)d_in[5];
    const float* Wg    = (const float*)d_in[6];
    const float* Wu    = (const float*)d_in[7];
    const float* Wd    = (const float*)d_in[8];
    float* out = (float*)d_out;
    char* ws = (char*)d_ws;

    float* xn1 = (float*)(ws + 0);
    float* Qb  = (float*)(ws + 8388608);
    float* Kb  = (float*)(ws + 16777216);
    float* Vb  = (float*)(ws + 25165824);
    float* ctx = (float*)(ws + 33554432);
    __hip_bfloat16* Hbuf = (__hip_bfloat16*)(ws + 0);         // reuses xn1/Q/K (dead)
    __hip_bfloat16* Ybuf = (__hip_bfloat16*)(ws + 25165824);  // reuses V (dead)
    float* x2  = (float*)(ws + 41943040);
    float* xn2 = (float*)(ws + 50331648);
    float* ct  = (float*)(ws + 58720256);
    float* st  = (float*)(ws + 58851328);
    int*   idx = (int*)(ws + 58982400);
    float* wts = (float*)(ws + 59047936);
    int* slotp = (int*)(ws + 59113472);
    int* ltok  = (int*)(ws + 59179008);
    int* cnt   = (int*)(ws + 59244544);
    int* offs  = cnt + 8;
    int* cur   = cnt + 16;
    float* imp = (float*)(cnt + 24);

    hipMemsetAsync(cnt, 0, 128, stream);

    rope_tables<<<128, 256, 0, stream>>>(ct, st);
    rmsnorm_k<<<8192, 256, 0, stream>>>(x, rms1w, xn1);
    gemm_qkv<<<dim3(12, 128), 256, 0, stream>>>(xn1, Wqkv, Qb, Kb, Vb);
    rope_k<<<4096, 256, 0, stream>>>(Qb, Kb, ct, st);
    attn_k<<<dim3(32, 32), 256, 0, stream>>>(Qb, Kb, Vb, ctx);
    gemm_out<<<dim3(4, 128), 256, 0, stream>>>(ctx, Wout, x, x2);
    rmsnorm_k<<<8192, 256, 0, stream>>>(x2, rms2w, xn2);
    gate_k<<<32, 256, 0, stream>>>(xn2, gateW, idx, wts, cnt, imp);
    prefix_k<<<1, 64, 0, stream>>>(cnt, imp, offs, cur, out + 2097152);
    scatter_k<<<32, 256, 0, stream>>>(idx, cur, ltok, slotp);
    moe_gemm1<<<dim3(12, 128, NE), 256, 0, stream>>>(xn2, Wg, Wu, cnt, offs, ltok, Hbuf);
    moe_gemm2<<<dim3(4, 128, NE), 256, 0, stream>>>(Hbuf, Wd, cnt, offs, Ybuf);
    combine_k<<<8192, 256, 0, stream>>>(x2, Ybuf, slotp, wts, out);
}

// Round 9
// 735.955 us; speedup vs baseline: 1.6810x; 1.2840x over previous
//
#include <hip/hip_runtime.h>
#include <hip/hip_bf16.h>
#include <math.h>

#define NE 6

typedef __bf16 bf16x8 __attribute__((ext_vector_type(8)));
typedef float f32x4 __attribute__((ext_vector_type(4)));
typedef short short8 __attribute__((ext_vector_type(8)));

// byte-offset swizzle within a [64 rows][64 k] bf16 LDS tile (row stride 128B)
#define SWZ(row, kbyte) (((row) * 128) + ((kbyte) ^ (((row) & 7) << 4)))

static __device__ __forceinline__ short f2bf(float f) {
    __hip_bfloat16 h = __float2bfloat16(f);
    return __builtin_bit_cast(short, h);
}

static __device__ __forceinline__ float bf2f(short s) {
    return __bfloat162float(__builtin_bit_cast(__hip_bfloat16, s));
}

// ---------------- RoPE tables ----------------
__global__ void rope_tables(float* __restrict__ ct, float* __restrict__ st) {
    int id = blockIdx.x * 256 + threadIdx.x;   // 2048*16
    if (id >= 2048 * 16) return;
    int s = id >> 4, f = id & 15;
    float invf = expf(-logf(10000.0f) * (float)f / 16.0f);
    float ang = (float)s * invf;
    ct[id] = cosf(ang);
    st[id] = sinf(ang);
}

// ---------------- RMSNorm (fp32 out) ----------------
__global__ void rmsnorm_k(const float* __restrict__ x, const float* __restrict__ w,
                          float* __restrict__ o) {
    __shared__ float red[256];
    int n = blockIdx.x, t = threadIdx.x;
    float v = x[n * 256 + t];
    red[t] = v * v;
    __syncthreads();
    for (int s = 128; s > 0; s >>= 1) {
        if (t < s) red[t] += red[t + s];
        __syncthreads();
    }
    float rms = rsqrtf(red[0] / 256.0f + 1e-6f);
    o[n * 256 + t] = v * rms * w[t];
}

// ---------------- RMSNorm (fp32 + bf16 out) ----------------
__global__ void rmsnorm_both(const float* __restrict__ x, const float* __restrict__ w,
                             float* __restrict__ o, short* __restrict__ obf) {
    __shared__ float red[256];
    int n = blockIdx.x, t = threadIdx.x;
    float v = x[n * 256 + t];
    red[t] = v * v;
    __syncthreads();
    for (int s = 128; s > 0; s >>= 1) {
        if (t < s) red[t] += red[t + s];
        __syncthreads();
    }
    float rms = rsqrtf(red[0] / 256.0f + 1e-6f);
    float val = v * rms * w[t];
    o[n * 256 + t] = val;
    obf[n * 256 + t] = f2bf(val);
}

// ---------------- tiled transpose + fp32->bf16: src[R][C] -> dst[C][R] ----------------
__global__ __launch_bounds__(256) void transcvt_k(const float* __restrict__ src,
                                                  short* __restrict__ dst, int R, int C) {
    __shared__ short tile[32][33];
    const float* s = src + (size_t)blockIdx.z * R * C;
    short* d = dst + (size_t)blockIdx.z * R * C;
    int t = threadIdx.x;
    int c0 = blockIdx.x * 32, r0 = blockIdx.y * 32;
    int ci = t & 31, ri0 = t >> 5;
#pragma unroll
    for (int it = 0; it < 4; it++) {
        int ri = ri0 + it * 8;
        tile[ri][ci] = f2bf(s[(size_t)(r0 + ri) * C + c0 + ci]);
    }
    __syncthreads();
#pragma unroll
    for (int it = 0; it < 4; it++) {
        int rj = ri0 + it * 8;
        d[(size_t)(c0 + rj) * R + r0 + ci] = tile[ci][rj];
    }
}

// ---------------- QKV GEMM (fp32, unchanged): scatter to Q/K/V (B,H,S,D) ----------------
__global__ __launch_bounds__(256) void gemm_qkv(const float* __restrict__ A,
                                                const float* __restrict__ W,
                                                float* __restrict__ Q, float* __restrict__ Kq,
                                                float* __restrict__ V) {
    __shared__ float As[16][64];
    __shared__ float Bs[16][64];
    int t = threadIdx.x;
    int m0 = blockIdx.y * 64, n0 = blockIdx.x * 64;
    float acc[4][4] = {};
    int am = t >> 2, ak = (t & 3) * 4;
    int bk = t >> 4, bn = (t & 15) * 4;
    int tm = (t & 15) * 4, tn = (t >> 4) * 4;
    for (int k0 = 0; k0 < 256; k0 += 16) {
        float4 av = *(const float4*)&A[(m0 + am) * 256 + k0 + ak];
        As[ak + 0][am] = av.x; As[ak + 1][am] = av.y; As[ak + 2][am] = av.z; As[ak + 3][am] = av.w;
        float4 bv = *(const float4*)&W[(k0 + bk) * 768 + n0 + bn];
        *(float4*)&Bs[bk][bn] = bv;
        __syncthreads();
#pragma unroll
        for (int kk = 0; kk < 16; kk++) {
            float4 a4 = *(float4*)&As[kk][tm];
            float4 b4 = *(float4*)&Bs[kk][tn];
            float a[4] = {a4.x, a4.y, a4.z, a4.w};
            float b[4] = {b4.x, b4.y, b4.z, b4.w};
#pragma unroll
            for (int i = 0; i < 4; i++)
#pragma unroll
                for (int j = 0; j < 4; j++) acc[i][j] += a[i] * b[j];
        }
        __syncthreads();
    }
    int part = n0 >> 8;
    float* dst = part == 0 ? Q : (part == 1 ? Kq : V);
#pragma unroll
    for (int i = 0; i < 4; i++) {
        int rowi = m0 + tm + i;
        int b = rowi >> 11, s = rowi & 2047;
#pragma unroll
        for (int j = 0; j < 4; j++) {
            int c = n0 + tn + j;
            int e = c & 255, h = e >> 5, d = e & 31;
            dst[(((size_t)(b * 8 + h)) * 2048 + s) * 32 + d] = acc[i][j];
        }
    }
}

// ---------------- RoPE in place on Q and K ----------------
__global__ void rope_k(float* __restrict__ Q, float* __restrict__ Kq,
                       const float* __restrict__ ct, const float* __restrict__ st) {
    int id = blockIdx.x * 256 + threadIdx.x;  // 32*2048*16
    if (id >= 32 * 2048 * 16) return;
    int i = id & 15;
    int s = (id >> 4) & 2047;
    int bh = id >> 15;
    int base = (bh * 2048 + s) * 32 + 2 * i;
    int j0 = (2 * i) & 15;
    float c0 = ct[s * 16 + j0], s0 = st[s * 16 + j0];
    float c1 = ct[s * 16 + j0 + 1], s1 = st[s * 16 + j0 + 1];
    float2 q = *(float2*)&Q[base];
    float2 k = *(float2*)&Kq[base];
    float2 qo, ko;
    qo.x = q.x * c0 - q.y * s0;
    qo.y = q.y * c1 + q.x * s1;
    ko.x = k.x * c0 - k.y * s0;
    ko.y = k.y * c1 + k.x * s1;
    *(float2*)&Q[base] = qo;
    *(float2*)&Kq[base] = ko;
}

// ---------------- Flash attention: 4 lanes per query row, 64 rows/block ----------------
__global__ __launch_bounds__(256) void attn_k(const float* __restrict__ Q,
                                              const float* __restrict__ Kg,
                                              const float* __restrict__ Vg,
                                              float* __restrict__ ctx) {
    __shared__ float4 Kl[64][8];
    __shared__ float4 Vl[64][8];
    int bh = blockIdx.x;
    int qt = gridDim.y - 1 - blockIdx.y;   // longest blocks launch first
    int t = threadIdx.x;
    int sub = t & 3;          // which 8-dim slice of D
    int row = qt * 64 + (t >> 2);
    const float4* Qb = (const float4*)(Q + (size_t)bh * 2048 * 32);
    const float4* Kb = (const float4*)(Kg + (size_t)bh * 2048 * 32);
    const float4* Vb = (const float4*)(Vg + (size_t)bh * 2048 * 32);
    float4 q0 = Qb[row * 8 + sub * 2];
    float4 q1 = Qb[row * 8 + sub * 2 + 1];
    float4 o0 = {}, o1 = {};
    float m = -1e30f, l = 0.f;
    const float scale = 0.17677669529663687f;  // 1/sqrt(32)
    int ntile = qt + 1;
    float4* Klf = &Kl[0][0];
    float4* Vlf = &Vl[0][0];
    for (int kt = 0; kt < ntile; kt++) {
        int kbase = kt * 64;
        Klf[t] = Kb[kbase * 8 + t];
        Klf[t + 256] = Kb[kbase * 8 + t + 256];
        Vlf[t] = Vb[kbase * 8 + t];
        Vlf[t + 256] = Vb[kbase * 8 + t + 256];
        __syncthreads();
        int jmax = row - kbase + 1;
        if (jmax > 64) jmax = 64;
        for (int j = 0; j < jmax; j++) {
            float4 k0 = Kl[j][sub * 2];
            float4 k1 = Kl[j][sub * 2 + 1];
            float s = q0.x * k0.x + q0.y * k0.y + q0.z * k0.z + q0.w * k0.w +
                      q1.x * k1.x + q1.y * k1.y + q1.z * k1.z + q1.w * k1.w;
            s += __shfl_xor(s, 1);
            s += __shfl_xor(s, 2);
            s *= scale;
            if (s > m) {
                float r = __expf(m - s);
                o0.x *= r; o0.y *= r; o0.z *= r; o0.w *= r;
                o1.x *= r; o1.y *= r; o1.z *= r; o1.w *= r;
                l *= r;
                m = s;
            }
            float p = __expf(s - m);
            l += p;
            float4 v0 = Vl[j][sub * 2];
            float4 v1 = Vl[j][sub * 2 + 1];
            o0.x += p * v0.x; o0.y += p * v0.y; o0.z += p * v0.z; o0.w += p * v0.w;
            o1.x += p * v1.x; o1.y += p * v1.y; o1.z += p * v1.z; o1.w += p * v1.w;
        }
        __syncthreads();
    }
    float invl = 1.f / l;
    int b = bh >> 3, h = bh & 7;
    float4* cp = (float4*)(ctx + ((size_t)(b * 2048 + row)) * 256 + h * 32 + sub * 8);
    o0.x *= invl; o0.y *= invl; o0.z *= invl; o0.w *= invl;
    o1.x *= invl; o1.y *= invl; o1.z *= invl; o1.w *= invl;
    cp[0] = o0;
    cp[1] = o1;
}

// ---------------- out projection + residual (fp32, unchanged) ----------------
__global__ __launch_bounds__(256) void gemm_out(const float* __restrict__ A,
                                                const float* __restrict__ W,
                                                const float* __restrict__ xres,
                                                float* __restrict__ x2) {
    __shared__ float As[16][64];
    __shared__ float Bs[16][64];
    int t = threadIdx.x;
    int m0 = blockIdx.y * 64, n0 = blockIdx.x * 64;
    float acc[4][4] = {};
    int am = t >> 2, ak = (t & 3) * 4;
    int bk = t >> 4, bn = (t & 15) * 4;
    int tm = (t & 15) * 4, tn = (t >> 4) * 4;
    for (int k0 = 0; k0 < 256; k0 += 16) {
        float4 av = *(const float4*)&A[(m0 + am) * 256 + k0 + ak];
        As[ak + 0][am] = av.x; As[ak + 1][am] = av.y; As[ak + 2][am] = av.z; As[ak + 3][am] = av.w;
        float4 bv = *(const float4*)&W[(k0 + bk) * 256 + n0 + bn];
        *(float4*)&Bs[bk][bn] = bv;
        __syncthreads();
#pragma unroll
        for (int kk = 0; kk < 16; kk++) {
            float4 a4 = *(float4*)&As[kk][tm];
            float4 b4 = *(float4*)&Bs[kk][tn];
            float a[4] = {a4.x, a4.y, a4.z, a4.w};
            float b[4] = {b4.x, b4.y, b4.z, b4.w};
#pragma unroll
            for (int i = 0; i < 4; i++)
#pragma unroll
                for (int j = 0; j < 4; j++) acc[i][j] += a[i] * b[j];
        }
        __syncthreads();
    }
#pragma unroll
    for (int i = 0; i < 4; i++) {
        int rowi = m0 + tm + i;
#pragma unroll
        for (int j = 0; j < 4; j++) {
            int c = n0 + tn + j;
            x2[rowi * 256 + c] = acc[i][j] + xres[rowi * 256 + c];
        }
    }
}

// ---------------- gate: logits, softmax, top-2, importance/counts ----------------
__global__ void gate_k(const float* __restrict__ xn2, const float* __restrict__ gw,
                       int* __restrict__ idx, float* __restrict__ wts,
                       int* __restrict__ cnt, float* __restrict__ imp) {
    __shared__ float simp[NE];
    __shared__ int scnt[NE];
    int t = threadIdx.x;
    int n = blockIdx.x * 256 + t;
    if (t < NE) { simp[t] = 0.f; scnt[t] = 0; }
    __syncthreads();
    float lg[NE] = {0, 0, 0, 0, 0, 0};
    for (int k = 0; k < 256; k++) {
        float xv = xn2[n * 256 + k];
#pragma unroll
        for (int e = 0; e < NE; e++) lg[e] += xv * gw[k * NE + e];
    }
    float mx = lg[0];
#pragma unroll
    for (int e = 1; e < NE; e++) mx = fmaxf(mx, lg[e]);
    float p[NE], se = 0.f;
#pragma unroll
    for (int e = 0; e < NE; e++) { p[e] = expf(lg[e] - mx); se += p[e]; }
    float inv = 1.f / se;
#pragma unroll
    for (int e = 0; e < NE; e++) p[e] *= inv;
    int i1 = 0; float v1 = p[0];
#pragma unroll
    for (int e = 1; e < NE; e++) if (p[e] > v1) { v1 = p[e]; i1 = e; }
    int i2 = -1; float v2 = -1.f;
#pragma unroll
    for (int e = 0; e < NE; e++) if (e != i1 && p[e] > v2) { v2 = p[e]; i2 = e; }
    float e2v = expf(v2 - v1);
    float w1 = 1.f / (1.f + e2v);
    float w2 = e2v / (1.f + e2v);
    idx[n * 2] = i1; idx[n * 2 + 1] = i2;
    wts[n * 2] = w1; wts[n * 2 + 1] = w2;
#pragma unroll
    for (int e = 0; e < NE; e++) atomicAdd(&simp[e], p[e]);
    atomicAdd(&scnt[i1], 1);
    atomicAdd(&scnt[i2], 1);
    __syncthreads();
    if (t < NE) {
        atomicAdd(&imp[t], simp[t]);
        atomicAdd(&cnt[t], scnt[t]);
    }
}

// ---------------- prefix sums + aux loss ----------------
__global__ void prefix_k(const int* __restrict__ cnt, const float* __restrict__ imp,
                         int* __restrict__ offs, int* __restrict__ cur,
                         float* __restrict__ auxout) {
    if (threadIdx.x == 0) {
        int o = 0;
        float a = 0.f;
        for (int e = 0; e < NE; e++) {
            offs[e] = o;
            cur[e] = o;
            o += cnt[e];
            a += imp[e] * (float)cnt[e];
        }
        auxout[0] = 6.0f * a / (8192.0f * 8192.0f);
    }
}

// ---------------- scatter token slots into expert buckets ----------------
__global__ void scatter_k(const int* __restrict__ idx, int* __restrict__ cur,
                          int* __restrict__ ltok, int* __restrict__ slotp) {
    int n = blockIdx.x * 256 + threadIdx.x;
#pragma unroll
    for (int s = 0; s < 2; s++) {
        int e = idx[n * 2 + s];
        int pos = atomicAdd(&cur[e], 1);
        ltok[pos] = n;
        slotp[n * 2 + s] = pos;
    }
}

// ---------------- MFMA expert GEMM 1: H = silu(A@Wg)*(A@Wu), gathered rows ----------------
// A: xn2 bf16 [8192][256] gathered via ltok; B: WgT/WuT bf16 [e][768][256] (n-major)
__global__ __launch_bounds__(256) void mfma_moe1(const short* __restrict__ xnbf,
                                                 const short* __restrict__ WgT,
                                                 const short* __restrict__ WuT,
                                                 const int* __restrict__ cnt,
                                                 const int* __restrict__ offs,
                                                 const int* __restrict__ ltok,
                                                 short* __restrict__ Hbuf) {
    int e = blockIdx.z;
    int Me = cnt[e];
    int m0 = blockIdx.y * 64;
    if (m0 >= Me) return;
    int off = offs[e];
    __shared__ short As[4096], Bg[4096], Bu[4096];
    __shared__ int stok[64];
    int t = threadIdx.x;
    if (t < 64) stok[t] = (m0 + t < Me) ? ltok[off + m0 + t] : ltok[off];
    __syncthreads();
    int n0 = blockIdx.x * 64;
    const short* WgE = WgT + (size_t)e * 768 * 256;
    const short* WuE = WuT + (size_t)e * 768 * 256;
    int lane = t & 63, wid = t >> 6, wr = wid >> 1, wc = wid & 1;
    int l15 = lane & 15, lh = lane >> 4;
    int r = t >> 3, k8 = (t & 7) * 8, kb8 = (t & 7) * 16;
    char* AsC = (char*)As; char* BgC = (char*)Bg; char* BuC = (char*)Bu;
    f32x4 accg[2][2] = {}, accu[2][2] = {};
    for (int k0 = 0; k0 < 256; k0 += 64) {
        short8 av0 = *(const short8*)&xnbf[(size_t)stok[r] * 256 + k0 + k8];
        short8 av1 = *(const short8*)&xnbf[(size_t)stok[r + 32] * 256 + k0 + k8];
        short8 gv0 = *(const short8*)&WgE[(size_t)(n0 + r) * 256 + k0 + k8];
        short8 gv1 = *(const short8*)&WgE[(size_t)(n0 + r + 32) * 256 + k0 + k8];
        short8 uv0 = *(const short8*)&WuE[(size_t)(n0 + r) * 256 + k0 + k8];
        short8 uv1 = *(const short8*)&WuE[(size_t)(n0 + r + 32) * 256 + k0 + k8];
        *(short8*)(AsC + SWZ(r, kb8)) = av0;
        *(short8*)(AsC + SWZ(r + 32, kb8)) = av1;
        *(short8*)(BgC + SWZ(r, kb8)) = gv0;
        *(short8*)(BgC + SWZ(r + 32, kb8)) = gv1;
        *(short8*)(BuC + SWZ(r, kb8)) = uv0;
        *(short8*)(BuC + SWZ(r + 32, kb8)) = uv1;
        __syncthreads();
#pragma unroll
        for (int kk = 0; kk < 2; kk++) {
            int kb = kk * 64 + lh * 16;
            bf16x8 a[2], bg[2], bu[2];
#pragma unroll
            for (int i = 0; i < 2; i++) {
                a[i]  = *(const bf16x8*)(AsC + SWZ(wr * 32 + i * 16 + l15, kb));
                bg[i] = *(const bf16x8*)(BgC + SWZ(wc * 32 + i * 16 + l15, kb));
                bu[i] = *(const bf16x8*)(BuC + SWZ(wc * 32 + i * 16 + l15, kb));
            }
#pragma unroll
            for (int mi = 0; mi < 2; mi++)
#pragma unroll
                for (int ni = 0; ni < 2; ni++) {
                    accg[mi][ni] = __builtin_amdgcn_mfma_f32_16x16x32_bf16(a[mi], bg[ni], accg[mi][ni], 0, 0, 0);
                    accu[mi][ni] = __builtin_amdgcn_mfma_f32_16x16x32_bf16(a[mi], bu[ni], accu[mi][ni], 0, 0, 0);
                }
        }
        __syncthreads();
    }
#pragma unroll
    for (int mi = 0; mi < 2; mi++)
#pragma unroll
        for (int j = 0; j < 4; j++) {
            int m = m0 + wr * 32 + mi * 16 + lh * 4 + j;
            if (m < Me) {
                size_t rp = (size_t)(off + m) * 768;
#pragma unroll
                for (int ni = 0; ni < 2; ni++) {
                    int c = n0 + wc * 32 + ni * 16 + l15;
                    float g = accg[mi][ni][j], u = accu[mi][ni][j];
                    Hbuf[rp + c] = f2bf(g / (1.f + __expf(-g)) * u);
                }
            }
        }
}

// ---------------- MFMA expert GEMM 2: Y = H @ Wd ----------------
// A: Hbuf bf16 [16384][768]; B: WdT bf16 [e][256][768] (n-major)
__global__ __launch_bounds__(256) void mfma_moe2(const short* __restrict__ Hbuf,
                                                 const short* __restrict__ WdT,
                                                 const int* __restrict__ cnt,
                                                 const int* __restrict__ offs,
                                                 short* __restrict__ Y) {
    int e = blockIdx.z;
    int Me = cnt[e];
    int m0 = blockIdx.y * 64;
    if (m0 >= Me) return;
    int off = offs[e];
    __shared__ short As[4096], Bs[4096];
    int t = threadIdx.x;
    int n0 = blockIdx.x * 64;
    const short* WdE = WdT + (size_t)e * 256 * 768;
    int lane = t & 63, wid = t >> 6, wr = wid >> 1, wc = wid & 1;
    int l15 = lane & 15, lh = lane >> 4;
    int r = t >> 3, k8 = (t & 7) * 8, kb8 = (t & 7) * 16;
    int ar0 = off + m0 + r;       if (ar0 > 16383) ar0 = 16383;
    int ar1 = off + m0 + r + 32;  if (ar1 > 16383) ar1 = 16383;
    char* AsC = (char*)As; char* BsC = (char*)Bs;
    f32x4 acc[2][2] = {};
    for (int k0 = 0; k0 < 768; k0 += 64) {
        short8 av0 = *(const short8*)&Hbuf[(size_t)ar0 * 768 + k0 + k8];
        short8 av1 = *(const short8*)&Hbuf[(size_t)ar1 * 768 + k0 + k8];
        short8 bv0 = *(const short8*)&WdE[(size_t)(n0 + r) * 768 + k0 + k8];
        short8 bv1 = *(const short8*)&WdE[(size_t)(n0 + r + 32) * 768 + k0 + k8];
        *(short8*)(AsC + SWZ(r, kb8)) = av0;
        *(short8*)(AsC + SWZ(r + 32, kb8)) = av1;
        *(short8*)(BsC + SWZ(r, kb8)) = bv0;
        *(short8*)(BsC + SWZ(r + 32, kb8)) = bv1;
        __syncthreads();
#pragma unroll
        for (int kk = 0; kk < 2; kk++) {
            int kb = kk * 64 + lh * 16;
            bf16x8 a[2], b[2];
#pragma unroll
            for (int i = 0; i < 2; i++) {
                a[i] = *(const bf16x8*)(AsC + SWZ(wr * 32 + i * 16 + l15, kb));
                b[i] = *(const bf16x8*)(BsC + SWZ(wc * 32 + i * 16 + l15, kb));
            }
#pragma unroll
            for (int mi = 0; mi < 2; mi++)
#pragma unroll
                for (int ni = 0; ni < 2; ni++)
                    acc[mi][ni] = __builtin_amdgcn_mfma_f32_16x16x32_bf16(a[mi], b[ni], acc[mi][ni], 0, 0, 0);
        }
        __syncthreads();
    }
#pragma unroll
    for (int mi = 0; mi < 2; mi++)
#pragma unroll
        for (int j = 0; j < 4; j++) {
            int m = m0 + wr * 32 + mi * 16 + lh * 4 + j;
            if (m < Me) {
                size_t rp = (size_t)(off + m) * 256;
#pragma unroll
                for (int ni = 0; ni < 2; ni++) {
                    int c = n0 + wc * 32 + ni * 16 + l15;
                    Y[rp + c] = f2bf(acc[mi][ni][j]);
                }
            }
        }
}

// ---------------- final combine: out = x2 + w0*Y[p0] + w1*Y[p1] ----------------
__global__ void combine_k(const float* __restrict__ x2, const short* __restrict__ Y,
                          const int* __restrict__ slotp, const float* __restrict__ wts,
                          float* __restrict__ out) {
    int n = blockIdx.x, t = threadIdx.x;
    int p0 = slotp[n * 2], p1 = slotp[n * 2 + 1];
    float w0 = wts[n * 2], w1 = wts[n * 2 + 1];
    out[n * 256 + t] = x2[n * 256 + t] + w0 * bf2f(Y[(size_t)p0 * 256 + t]) +
                       w1 * bf2f(Y[(size_t)p1 * 256 + t]);
}

extern "C" void kernel_launch(void* const* d_in, const int* in_sizes, int n_in,
                              void* d_out, int out_size, void* d_ws, size_t ws_size,
                              hipStream_t stream) {
    const float* x     = (const float*)d_in[0];
    const float* Wqkv  = (const float*)d_in[1];
    const float* Wout  = (const float*)d_in[2];
    const float* rms1w = (const float*)d_in[3];
    const float* rms2w = (const float*)d_in[4];
    const float* gateW = (const float*)d_in[5];
    const float* Wg    = (const float*)d_in[6];
    const float* Wu    = (const float*)d_in[7];
    const float* Wd    = (const float*)d_in[8];
    float* out = (float*)d_out;
    char* ws = (char*)d_ws;

    // region 0..8MB: xn1 fp32 (dead after qkv) -> xn2bf (4MB, written at rms2)
    float* xn1   = (float*)(ws + 0);
    short* xn2bf = (short*)(ws + 0);
    float* Qb  = (float*)(ws + 8388608);
    float* Kb  = (float*)(ws + 16777216);
    float* Vb  = (float*)(ws + 25165824);
    // Hbuf bf16 25.17MB over Q/K/V (dead after attn): 4194304..29360128
    short* Hbuf = (short*)(ws + 4194304);
    float* ctx = (float*)(ws + 33554432);   // dead after gemm_out
    // weight transposes in dead ctx region (written after gemm_out)
    short* WgT = (short*)(ws + 33554432);
    short* WuT = (short*)(ws + 35913728);
    short* WdT = (short*)(ws + 38273024);
    float* x2  = (float*)(ws + 41943040);
    float* xn2 = (float*)(ws + 50331648);   // dead after gate
    short* Ybuf = (short*)(ws + 50331648);  // written at moe2
    float* ct  = (float*)(ws + 58720256);
    float* st  = (float*)(ws + 58851328);
    int*   idx = (int*)(ws + 58982400);
    float* wts = (float*)(ws + 59047936);
    int* slotp = (int*)(ws + 59113472);
    int* ltok  = (int*)(ws + 59179008);
    int* cnt   = (int*)(ws + 59244544);
    int* offs  = cnt + 8;
    int* cur   = cnt + 16;
    float* imp = (float*)(cnt + 24);

    (void)hipMemsetAsync(cnt, 0, 128, stream);

    rope_tables<<<128, 256, 0, stream>>>(ct, st);
    rmsnorm_k<<<8192, 256, 0, stream>>>(x, rms1w, xn1);
    gemm_qkv<<<dim3(12, 128), 256, 0, stream>>>(xn1, Wqkv, Qb, Kb, Vb);
    rope_k<<<4096, 256, 0, stream>>>(Qb, Kb, ct, st);
    attn_k<<<dim3(32, 32), 256, 0, stream>>>(Qb, Kb, Vb, ctx);
    gemm_out<<<dim3(4, 128), 256, 0, stream>>>(ctx, Wout, x, x2);
    // ctx now dead: build bf16 transposed weights for MoE
    transcvt_k<<<dim3(24, 8, NE), 256, 0, stream>>>(Wg, WgT, 256, 768);
    transcvt_k<<<dim3(24, 8, NE), 256, 0, stream>>>(Wu, WuT, 256, 768);
    transcvt_k<<<dim3(8, 24, NE), 256, 0, stream>>>(Wd, WdT, 768, 256);
    rmsnorm_both<<<8192, 256, 0, stream>>>(x2, rms2w, xn2, xn2bf);
    gate_k<<<32, 256, 0, stream>>>(xn2, gateW, idx, wts, cnt, imp);
    prefix_k<<<1, 64, 0, stream>>>(cnt, imp, offs, cur, out + 2097152);
    scatter_k<<<32, 256, 0, stream>>>(idx, cur, ltok, slotp);
    mfma_moe1<<<dim3(12, 256, NE), 256, 0, stream>>>(xn2bf, WgT, WuT, cnt, offs, ltok, Hbuf);
    mfma_moe2<<<dim3(4, 256, NE), 256, 0, stream>>>(Hbuf, WdT, cnt, offs, Ybuf);
    combine_k<<<8192, 256, 0, stream>>>(x2, Ybuf, slotp, wts, out);
}